// Round 17
// baseline (146.431 us; speedup 1.0000x reference)
//
#include <hip/hip_runtime.h>
#include <math.h>

#define BB 64
#define FF 64
#define GG 512
#define NN 16384
#define PTOT (BB*NN)          // 1048576
#define EPSF 1e-6f
#define BN_EPSF 1e-5f

// ws float offsets
#define WS_HBUF   0           // [4][4096] film phase-1 partials (zeroed)
#define WS_MOM    16384       // 5 moments + pad -> 16392
#define WS_COEF   16648       // [2][64][4] (A,B,C,pad) -> 17160
#define WS_FILMW  17416       // [2][64*64] -> 25608
#define WS_FILMB  25608       // [2][64*64] -> 33800
#define WS_WB     33800       // bf16 W, ushort[2][64][64] = 4096 floats -> 37896
#define WS_PC     37896       // [2][64][64][4] {s,t,w2,0} -> 70664
#define WS_PART   70664       // [1024][4][64] h2stats partials -> 332808
#define WS_ZERO_FLOATS 16648

#define OFF_MU  (BB*3*NN)
#define OFF_LV  (2*BB*3*NN)

typedef __attribute__((ext_vector_type(8))) short short8_t;
typedef __attribute__((ext_vector_type(4))) float f32x4;
typedef __attribute__((ext_vector_type(2))) float f32x2;

__device__ __forceinline__ unsigned int bf16u(float x) {
    unsigned int u = __float_as_uint(x);
    return ((u + 0x7FFFu + ((u >> 16) & 1u)) >> 16) & 0xFFFFu;   // RNE
}
__device__ __forceinline__ f32x2 pk_fma(f32x2 a, f32x2 b, f32x2 c) {
    f32x2 d;
    asm("v_pk_fma_f32 %0, %1, %2, %3" : "=v"(d) : "v"(a), "v"(b), "v"(c));
    return d;
}
__device__ __forceinline__ f32x2 pk_add(f32x2 a, f32x2 b) {
    f32x2 d;
    asm("v_pk_add_f32 %0, %1, %2" : "=v"(d) : "v"(a), "v"(b));
    return d;
}

// ---------------- FiLM phase 1: H_partial = g[:,kc] @ W0[:,kc]^T, K-split ----------------
__global__ __launch_bounds__(256) void k_filmA(
    const float* __restrict__ g,
    const float* __restrict__ W0_0, const float* __restrict__ W0_1,
    const float* __restrict__ W0_2, const float* __restrict__ W0_3,
    float* __restrict__ ws) {
    __shared__ float g_tile[64][65];
    __shared__ float wT[64][69];
    const int combo = blockIdx.x;
    const int kbase = blockIdx.y * 64;
    const int t = threadIdx.x;
    const float* W0 = combo==0 ? W0_0 : combo==1 ? W0_1 : combo==2 ? W0_2 : W0_3;
    float* hb = ws + WS_HBUF + combo*4096;

#pragma unroll
    for (int n = 0; n < 4; ++n) {
        const int idx = t + n*256;             // 0..1023 float4s
        const int row = idx >> 4, k4 = idx & 15;
        const float4 gv = *(const float4*)(g  + row*GG + kbase + k4*4);
        const float4 wv = *(const float4*)(W0 + row*GG + kbase + k4*4);
        g_tile[row][k4*4+0] = gv.x; g_tile[row][k4*4+1] = gv.y;
        g_tile[row][k4*4+2] = gv.z; g_tile[row][k4*4+3] = gv.w;
        wT[k4*4+0][row] = wv.x; wT[k4*4+1][row] = wv.y;
        wT[k4*4+2][row] = wv.z; wT[k4*4+3][row] = wv.w;
    }
    __syncthreads();

    const int b0 = (t >> 3) * 2, f0 = (t & 7) * 8;
    float acc[2][8];
#pragma unroll
    for (int i = 0; i < 2; ++i)
#pragma unroll
        for (int j = 0; j < 8; ++j) acc[i][j] = 0.f;
#pragma unroll 4
    for (int k = 0; k < 64; ++k) {
        const float g0 = g_tile[b0][k], g1 = g_tile[b0+1][k];
        const float4 w01 = *(const float4*)&wT[k][f0];
        const float4 w23 = *(const float4*)&wT[k][f0+4];
        const float wv[8] = {w01.x,w01.y,w01.z,w01.w,w23.x,w23.y,w23.z,w23.w};
#pragma unroll
        for (int j = 0; j < 8; ++j) {
            acc[0][j] = fmaf(g0, wv[j], acc[0][j]);
            acc[1][j] = fmaf(g1, wv[j], acc[1][j]);
        }
    }
#pragma unroll
    for (int i = 0; i < 2; ++i)
#pragma unroll
        for (int j = 0; j < 8; ++j)
            atomicAdd(&hb[(b0+i)*64 + f0+j], acc[i][j]);
}

// ---------------- FiLM phase 2+3: BN + SiLU + h @ W1^T + b1 ----------------
__global__ __launch_bounds__(256) void k_filmB(
    const float* __restrict__ bng_0, const float* __restrict__ bnb_0,
    const float* __restrict__ W1_0,  const float* __restrict__ b1_0,
    const float* __restrict__ bng_1, const float* __restrict__ bnb_1,
    const float* __restrict__ W1_1,  const float* __restrict__ b1_1,
    const float* __restrict__ bng_2, const float* __restrict__ bnb_2,
    const float* __restrict__ W1_2,  const float* __restrict__ b1_2,
    const float* __restrict__ bng_3, const float* __restrict__ bnb_3,
    const float* __restrict__ W1_3,  const float* __restrict__ b1_3,
    float* __restrict__ ws) {
    __shared__ float H[64][65];
    __shared__ float S[64][65];
    __shared__ float W1T[64][69];
    const int combo = blockIdx.x;
    const int t = threadIdx.x;
    const float* bng = combo==0 ? bng_0 : combo==1 ? bng_1 : combo==2 ? bng_2 : bng_3;
    const float* bnb = combo==0 ? bnb_0 : combo==1 ? bnb_1 : combo==2 ? bnb_2 : bnb_3;
    const float* W1  = combo==0 ? W1_0  : combo==1 ? W1_1  : combo==2 ? W1_2  : W1_3;
    const float* b1  = combo==0 ? b1_0  : combo==1 ? b1_1  : combo==2 ? b1_2  : b1_3;
    const float* hb  = ws + WS_HBUF + combo*4096;
    float* outp = ws + ((combo & 1) ? WS_FILMB : WS_FILMW) + (combo >> 1) * 4096;

    for (int idx = t; idx < 4096; idx += 256) H[idx >> 6][idx & 63] = hb[idx];
    {   // stage W1 transposed (W1 is 64x64: row = idx>>4, col4 = idx&15)
#pragma unroll
        for (int n = 0; n < 4; ++n) {
            const int idx = t + n*256;          // 0..1023 float4s
            const int f2 = idx >> 4, k4 = idx & 15;
            const float4 wv = *(const float4*)(W1 + f2*64 + k4*4);
            W1T[k4*4+0][f2] = wv.x; W1T[k4*4+1][f2] = wv.y;
            W1T[k4*4+2][f2] = wv.z; W1T[k4*4+3][f2] = wv.w;
        }
    }
    __syncthreads();
    for (int idx = t; idx < 4096; idx += 256) {
        const int b = idx >> 6, f = idx & 63;
        float m = 0.f;
        for (int b2 = 0; b2 < 64; ++b2) m += H[b2][f];
        m *= (1.f/64.f);
        float v = 0.f;
        for (int b2 = 0; b2 < 64; ++b2) { const float d = H[b2][f] - m; v = fmaf(d, d, v); }
        v *= (1.f/64.f);
        const float xh = (H[b][f] - m) * rsqrtf(v + BN_EPSF) * bng[f] + bnb[f];
        S[b][f] = xh / (1.f + expf(-xh));   // SiLU
    }
    __syncthreads();
    const int b0 = (t >> 3) * 2, f0 = (t & 7) * 8;
    float acc[2][8];
#pragma unroll
    for (int i = 0; i < 2; ++i)
#pragma unroll
        for (int j = 0; j < 8; ++j) acc[i][j] = 0.f;
#pragma unroll 4
    for (int k = 0; k < 64; ++k) {
        const float s0 = S[b0][k], s1 = S[b0+1][k];
        const float4 w01 = *(const float4*)&W1T[k][f0];
        const float4 w23 = *(const float4*)&W1T[k][f0+4];
        const float wv[8] = {w01.x,w01.y,w01.z,w01.w,w23.x,w23.y,w23.z,w23.w};
#pragma unroll
        for (int j = 0; j < 8; ++j) {
            acc[0][j] = fmaf(s0, wv[j], acc[0][j]);
            acc[1][j] = fmaf(s1, wv[j], acc[1][j]);
        }
    }
#pragma unroll
    for (int i = 0; i < 2; ++i)
#pragma unroll
        for (int j = 0; j < 8; ++j)
            outp[(b0+i)*64 + f0+j] = acc[i][j] + b1[f0+j];
}

// ---------------- global moments of (u,v) ----------------
__global__ __launch_bounds__(256) void k_moments(const float* __restrict__ p, float* __restrict__ ws) {
    __shared__ float red[4][8];
    const int t = threadIdx.x;
    const int gid = blockIdx.x * 256 + t;      // 131072 threads, 8 pos each
    const int pos8 = gid << 3;
    const int b = pos8 >> 14, n = pos8 & 16383;
    const float* base = p + (size_t)b*3*NN + NN + n;
    const float4 ua = *(const float4*)base;
    const float4 ub = *(const float4*)(base + 4);
    const float4 va = *(const float4*)(base + NN);
    const float4 vb = *(const float4*)(base + NN + 4);
    float su  = (ua.x+ua.y)+(ua.z+ua.w)+(ub.x+ub.y)+(ub.z+ub.w);
    float sv  = (va.x+va.y)+(va.z+va.w)+(vb.x+vb.y)+(vb.z+vb.w);
    float suu = fmaf(ua.x,ua.x, fmaf(ua.y,ua.y, fmaf(ua.z,ua.z, ua.w*ua.w)))
              + fmaf(ub.x,ub.x, fmaf(ub.y,ub.y, fmaf(ub.z,ub.z, ub.w*ub.w)));
    float svv = fmaf(va.x,va.x, fmaf(va.y,va.y, fmaf(va.z,va.z, va.w*va.w)))
              + fmaf(vb.x,vb.x, fmaf(vb.y,vb.y, fmaf(vb.z,vb.z, vb.w*vb.w)));
    float suv = fmaf(ua.x,va.x, fmaf(ua.y,va.y, fmaf(ua.z,va.z, ua.w*va.w)))
              + fmaf(ub.x,vb.x, fmaf(ub.y,vb.y, fmaf(ub.z,vb.z, ub.w*vb.w)));
#pragma unroll
    for (int off = 32; off > 0; off >>= 1) {
        su  += __shfl_down(su,  off);
        sv  += __shfl_down(sv,  off);
        suu += __shfl_down(suu, off);
        svv += __shfl_down(svv, off);
        suv += __shfl_down(suv, off);
    }
    const int w = t >> 6;
    if ((t & 63) == 0) {
        red[w][0] = su; red[w][1] = sv; red[w][2] = suu; red[w][3] = svv; red[w][4] = suv;
    }
    __syncthreads();
    if (t < 5)
        atomicAdd(&ws[WS_MOM + t], red[0][t] + red[1][t] + red[2][t] + red[3][t]);
}

// ---------------- BN1 coefs (closed form from moments); build bf16 W ----------------
__global__ __launch_bounds__(256) void k_coef2(const float* __restrict__ lvW, const float* __restrict__ lvG,
                                               const float* __restrict__ lvB, const float* __restrict__ muW,
                                               const float* __restrict__ muG, const float* __restrict__ muB,
                                               const float* __restrict__ lvW1, const float* __restrict__ muW1,
                                               float* __restrict__ ws) {
    const int t = threadIdx.x;
    const int bid = blockIdx.x;
    if (bid == 0 && t < 128) {
        const int br = t >> 6, c = t & 63;
        const float* W  = br ? muW : lvW;
        const float* Gp = br ? muG : lvG;
        const float* Bp = br ? muB : lvB;
        const float inv = 1.f / (float)PTOT;
        const float Eu  = ws[WS_MOM+0]*inv, Ev  = ws[WS_MOM+1]*inv;
        const float Euu = ws[WS_MOM+2]*inv, Evv = ws[WS_MOM+3]*inv, Euv = ws[WS_MOM+4]*inv;
        const float w0 = W[c*2 + 0], w1 = W[c*2 + 1];
        const float m   = w0*Eu + w1*Ev;
        const float e2  = w0*w0*Euu + 2.f*w0*w1*Euv + w1*w1*Evv;
        const float var = e2 - m*m;
        const float rs  = rsqrtf(var + BN_EPSF);
        const float ga = Gp[c], be = Bp[c];
        float4 cf;
        cf.x = w0*rs*ga; cf.y = w1*rs*ga; cf.z = be - m*rs*ga; cf.w = 0.f;
        *(float4*)(ws + WS_COEF + (br*64+c)*4) = cf;
    }
    // bf16 copy of sd1_W, row-major [br][c][k] — disjoint 2048-element slices per block
    unsigned short* wb = (unsigned short*)(ws + WS_WB);
    for (int e = bid*2048 + t; e < bid*2048 + 2048; e += 256) {
        const int brx = e >> 12, r = e & 4095;
        wb[e] = (unsigned short)bf16u((brx ? muW1 : lvW1)[r]);
    }
}

// ---------------- BN2 stats: dual-branch, packed-f32, interleaved uv, no atomics ----------------
__global__ __launch_bounds__(256) void k_h2stats(const float* __restrict__ p, float* __restrict__ ws) {
    __shared__ __align__(16) float uvS[1024][2];
    __shared__ float red1[2][4][64];
    __shared__ float red2[2][4][64];
    const int t = threadIdx.x;
    const int bid = blockIdx.x;
    const int b = bid >> 4;
    const int n0 = (bid & 15) * 1024;          // 1024 positions per block
    const float* pk = p + (size_t)b*3*NN + NN;
    {   // stage u,v interleaved
        const float4 u4 = *(const float4*)(pk + n0 + t*4);
        const float4 v4 = *(const float4*)(pk + NN + n0 + t*4);
        float4 a0; a0.x = u4.x; a0.y = v4.x; a0.z = u4.y; a0.w = v4.y;
        float4 a1; a1.x = u4.z; a1.y = v4.z; a1.z = u4.w; a1.w = v4.w;
        *(float4*)&uvS[t*4][0]     = a0;
        *(float4*)&uvS[t*4 + 2][0] = a1;
    }
    __syncthreads();
    const int w = t >> 6, lane = t & 63, g = lane >> 4, col = lane & 15;
    const unsigned short* wbg = (const unsigned short*)(ws + WS_WB);

#pragma unroll 1
    for (int br = 0; br < 2; ++br) {
        f32x2 cA2[8], cB2[8], cC2[8];
#pragma unroll
        for (int kt = 0; kt < 2; ++kt)
#pragma unroll
            for (int q = 0; q < 4; ++q) {
                const int pi = kt*4 + q, ch = kt*32 + g*8 + q*2;
                const float4 c0 = *(const float4*)(ws + WS_COEF + (br*64 + ch)*4);
                const float4 c1 = *(const float4*)(ws + WS_COEF + (br*64 + ch + 1)*4);
                cA2[pi] = (f32x2){c0.x, c1.x};
                cB2[pi] = (f32x2){c0.y, c1.y};
                cC2[pi] = (f32x2){c0.z, c1.z};
            }
        short8_t a[4][2];
#pragma unroll
        for (int mt = 0; mt < 4; ++mt)
#pragma unroll
            for (int kt = 0; kt < 2; ++kt)
                a[mt][kt] = *(const short8_t*)(wbg + br*4096 + (mt*16+col)*64 + kt*32 + g*8);
        f32x2 s1v[8], s2v[8];
#pragma unroll
        for (int i = 0; i < 8; ++i) { s1v[i] = (f32x2){0.f,0.f}; s2v[i] = (f32x2){0.f,0.f}; }

#pragma unroll 4
        for (int nt = 0; nt < 16; ++nt) {      // wave-owned n-tiles
            const int pl = (nt*4 + w)*16 + col;
            const f32x2 uv = *(const f32x2*)&uvS[pl][0];
            const f32x2 uu = (f32x2){uv.x, uv.x};
            const f32x2 vv = (f32x2){uv.y, uv.y};
            union { uint4 u4; short8_t s8; } bf[2];
#pragma unroll
            for (int kt = 0; kt < 2; ++kt) {
                unsigned int dw[4];
#pragma unroll
                for (int q = 0; q < 4; ++q) {
                    const int pi = kt*4 + q;
                    const f32x2 h2v = pk_fma(cA2[pi], uu, pk_fma(cB2[pi], vv, cC2[pi]));
                    const float h0 = fmaxf(h2v.x, 0.f);
                    const float h1 = fmaxf(h2v.y, 0.f);
                    asm("v_cvt_pk_bf16_f32 %0, %1, %2" : "=v"(dw[q]) : "v"(h0), "v"(h1));
                }
                bf[kt].u4 = make_uint4(dw[0], dw[1], dw[2], dw[3]);
            }
            f32x4 acc[4];
#pragma unroll
            for (int mt = 0; mt < 4; ++mt) { f32x4 z = {0.f,0.f,0.f,0.f}; acc[mt] = z; }
#pragma unroll
            for (int mt = 0; mt < 4; ++mt) {
                acc[mt] = __builtin_amdgcn_mfma_f32_16x16x32_bf16(a[mt][0], bf[0].s8, acc[mt], 0,0,0);
                acc[mt] = __builtin_amdgcn_mfma_f32_16x16x32_bf16(a[mt][1], bf[1].s8, acc[mt], 0,0,0);
            }
#pragma unroll
            for (int mt = 0; mt < 4; ++mt)
#pragma unroll
                for (int rr = 0; rr < 2; ++rr) {
                    const int pi = mt*2 + rr;
                    const f32x2 xp = (f32x2){acc[mt][rr*2], acc[mt][rr*2+1]};
                    s1v[pi] = pk_add(s1v[pi], xp);
                    s2v[pi] = pk_fma(xp, xp, s2v[pi]);
                }
        }
        // cross-lane reduce each half over the 16 p-columns
#pragma unroll
        for (int pi = 0; pi < 8; ++pi) {
            float a1x = s1v[pi].x, a1y = s1v[pi].y, a2x = s2v[pi].x, a2y = s2v[pi].y;
#pragma unroll
            for (int off = 1; off <= 8; off <<= 1) {
                a1x += __shfl_xor(a1x, off);
                a1y += __shfl_xor(a1y, off);
                a2x += __shfl_xor(a2x, off);
                a2y += __shfl_xor(a2y, off);
            }
            s1v[pi] = (f32x2){a1x, a1y};
            s2v[pi] = (f32x2){a2x, a2y};
        }
        if (col == 0) {
#pragma unroll
            for (int mt = 0; mt < 4; ++mt)
#pragma unroll
                for (int r = 0; r < 4; ++r) {
                    const int c = mt*16 + g*4 + r;
                    const int pi = mt*2 + (r >> 1);
                    red1[br][w][c] = (r & 1) ? s1v[pi].y : s1v[pi].x;
                    red2[br][w][c] = (r & 1) ? s2v[pi].y : s2v[pi].x;
                }
        }
    }
    __syncthreads();
    {   // disjoint per-block partial store
        const int kind = t >> 6, c = t & 63;
        const int br2 = kind >> 1, sk = kind & 1;
        const float* rr = sk ? &red2[br2][0][0] : &red1[br2][0][0];
        ws[WS_PART + bid*256 + (br2*2 + sk)*64 + c] =
            rr[0*64 + c] + rr[1*64 + c] + rr[2*64 + c] + rr[3*64 + c];
    }
}

// ---------------- reduce partials -> stats -> PC table (one block per (br,c)) ----------------
__global__ __launch_bounds__(256) void k_redpc(const float* __restrict__ lv_sd2W,
                                               const float* __restrict__ mu_sd2W,
                                               float* __restrict__ ws) {
    __shared__ float a1[4], a2[4];
    __shared__ float stats[2];
    const int idx = blockIdx.x;        // 0..127 => br*64 + c
    const int br = idx >> 6, c = idx & 63;
    const int t = threadIdx.x;
    float s1 = 0.f, s2 = 0.f;
    for (int j = t; j < 1024; j += 256) {
        const float* pp = ws + WS_PART + j*256;
        s1 += pp[(br*2 + 0)*64 + c];
        s2 += pp[(br*2 + 1)*64 + c];
    }
#pragma unroll
    for (int off = 32; off > 0; off >>= 1) {
        s1 += __shfl_down(s1, off);
        s2 += __shfl_down(s2, off);
    }
    if ((t & 63) == 0) { a1[t >> 6] = s1; a2[t >> 6] = s2; }
    __syncthreads();
    if (t == 0) {
        const float S1 = a1[0]+a1[1]+a1[2]+a1[3];
        const float S2 = a2[0]+a2[1]+a2[2]+a2[3];
        const float inv = 1.f / (float)PTOT;
        const float m2 = S1 * inv, e2 = S2 * inv;
        stats[0] = m2;
        stats[1] = rsqrtf(e2 - m2*m2 + BN_EPSF);
    }
    __syncthreads();
    if (t < 64) {   // PC[br][b][c] for all 64 batches of this (br,c)
        const int b = t;
        const float m2  = stats[0], rs2 = stats[1];
        const float fw  = ws[WS_FILMW + br*4096 + b*64 + c];
        const float fb  = ws[WS_FILMB + br*4096 + b*64 + c];
        const float s = (EPSF + expf(fw)) * rs2;
        float4 pc;
        pc.x = s; pc.y = fb - s*m2; pc.z = (br ? mu_sd2W : lv_sd2W)[c]; pc.w = 0.f;
        *(float4*)(ws + WS_PC + ((br*64 + b)*64 + c)*4) = pc;
    }
}

// ---------------- main pass: packed-f32 + MFMA + fused epilogue ----------------
__global__ __launch_bounds__(256) void k_main(
    const float* __restrict__ p,
    const float* __restrict__ lv_sd2b, const float* __restrict__ mu_sd2b,
    const float* __restrict__ ws, float* __restrict__ out)
{
    __shared__ float xS[1024];
    __shared__ __align__(16) float uvS[1024][2];
    __shared__ __align__(16) float pcS[2][64][4];
    __shared__ float resS[1024];

    const int t   = threadIdx.x;
    const int bid = blockIdx.x;
    const int b   = bid >> 4;
    const int n0  = (bid & 15) * 1024;         // 1024 positions per block
    const size_t pb = (size_t)b * 3 * NN;
    const float* pk = p + pb + NN;

    // stage x0 + interleaved u,v + per-(br,c) epilogue constants
    *(float4*)&xS[t*4] = *(const float4*)(p + pb + n0 + t*4);
    {
        const float4 u4 = *(const float4*)(pk + n0 + t*4);
        const float4 v4 = *(const float4*)(pk + NN + n0 + t*4);
        float4 a0; a0.x = u4.x; a0.y = v4.x; a0.z = u4.y; a0.w = v4.y;
        float4 a1; a1.x = u4.z; a1.y = v4.z; a1.z = u4.w; a1.w = v4.w;
        *(float4*)&uvS[t*4][0]     = a0;
        *(float4*)&uvS[t*4 + 2][0] = a1;
    }
    if (t < 128) {
        const int br = t >> 6, c = t & 63;
        *(float4*)&pcS[br][c][0] = *(const float4*)(ws + WS_PC + ((br*64 + b)*64 + c)*4);
    }
    __syncthreads();

    const int w = t >> 6, lane = t & 63, g = lane >> 4, col = lane & 15;
    const unsigned short* wbg = (const unsigned short*)(ws + WS_WB);
    const float sd2b0 = lv_sd2b[0], sd2b1 = mu_sd2b[0];

#pragma unroll 1
    for (int br = 0; br < 2; ++br) {
        f32x2 cA2[8], cB2[8], cC2[8];
#pragma unroll
        for (int kt = 0; kt < 2; ++kt)
#pragma unroll
            for (int q = 0; q < 4; ++q) {
                const int pi = kt*4 + q, ch = kt*32 + g*8 + q*2;
                const float4 c0 = *(const float4*)(ws + WS_COEF + (br*64 + ch)*4);
                const float4 c1 = *(const float4*)(ws + WS_COEF + (br*64 + ch + 1)*4);
                cA2[pi] = (f32x2){c0.x, c1.x};
                cB2[pi] = (f32x2){c0.y, c1.y};
                cC2[pi] = (f32x2){c0.z, c1.z};
            }
        short8_t a[4][2];
#pragma unroll
        for (int mt = 0; mt < 4; ++mt)
#pragma unroll
            for (int kt = 0; kt < 2; ++kt)
                a[mt][kt] = *(const short8_t*)(wbg + br*4096 + (mt*16+col)*64 + kt*32 + g*8);
        f32x2 sp2[8], tq2[8], w2v2[8];
#pragma unroll
        for (int mt = 0; mt < 4; ++mt)
#pragma unroll
            for (int rr = 0; rr < 2; ++rr) {
                const int pi = mt*2 + rr, c0i = mt*16 + g*4 + rr*2;
                const float4 p0 = *(const float4*)&pcS[br][c0i][0];
                const float4 p1 = *(const float4*)&pcS[br][c0i+1][0];
                sp2[pi]  = (f32x2){p0.x, p1.x};
                tq2[pi]  = (f32x2){p0.y, p1.y};
                w2v2[pi] = (f32x2){p0.z, p1.z};
            }

#pragma unroll 4
        for (int nt = 0; nt < 16; ++nt) {      // wave-owned n-tiles
            const int pl = (nt*4 + w)*16 + col;
            const f32x2 uv = *(const f32x2*)&uvS[pl][0];
            const f32x2 uu = (f32x2){uv.x, uv.x};
            const f32x2 vv = (f32x2){uv.y, uv.y};
            union { uint4 u4; short8_t s8; } bf[2];
#pragma unroll
            for (int kt = 0; kt < 2; ++kt) {
                unsigned int dw[4];
#pragma unroll
                for (int q = 0; q < 4; ++q) {
                    const int pi = kt*4 + q;
                    const f32x2 h2v = pk_fma(cA2[pi], uu, pk_fma(cB2[pi], vv, cC2[pi]));
                    const float h0 = fmaxf(h2v.x, 0.f);
                    const float h1 = fmaxf(h2v.y, 0.f);
                    asm("v_cvt_pk_bf16_f32 %0, %1, %2" : "=v"(dw[q]) : "v"(h0), "v"(h1));
                }
                bf[kt].u4 = make_uint4(dw[0], dw[1], dw[2], dw[3]);
            }
            f32x4 acc[4];
#pragma unroll
            for (int mt = 0; mt < 4; ++mt) { f32x4 z = {0.f,0.f,0.f,0.f}; acc[mt] = z; }
#pragma unroll
            for (int mt = 0; mt < 4; ++mt) {
                acc[mt] = __builtin_amdgcn_mfma_f32_16x16x32_bf16(a[mt][0], bf[0].s8, acc[mt], 0,0,0);
                acc[mt] = __builtin_amdgcn_mfma_f32_16x16x32_bf16(a[mt][1], bf[1].s8, acc[mt], 0,0,0);
            }
            f32x2 po2 = (f32x2){0.f, 0.f};
#pragma unroll
            for (int mt = 0; mt < 4; ++mt)
#pragma unroll
                for (int rr = 0; rr < 2; ++rr) {
                    const int pi = mt*2 + rr;
                    f32x2 hf = pk_fma((f32x2){acc[mt][rr*2], acc[mt][rr*2+1]}, sp2[pi], tq2[pi]);
                    hf.x = fmaxf(hf.x, 0.f);
                    hf.y = fmaxf(hf.y, 0.f);
                    po2 = pk_fma(hf, w2v2[pi], po2);
                }
            float po = po2.x + po2.y;
            po += __shfl_xor(po, 16);
            po += __shfl_xor(po, 32);
            if (br == 0) {
                if (lane < 16) resS[pl] = po;    // same-wave write/read, no barrier needed
            } else {
                const float ol = resS[pl] + sd2b0;
                const float om = po + sd2b1;
                const float lw = ol / (1.f + fabsf(ol));
                const float sc = sqrtf(EPSF + expf(lw));
                const size_t nix = pb + n0 + pl;
                if (g == 0) {
                    out[nix] = fmaf(sc, xS[pl], om);
                } else if (g == 1) {
                    out[OFF_MU + nix] = om;
                } else if (g == 2) {
                    out[OFF_LV + nix] = lw;
                }
            }
        }
    }
    // channels 1,2 pass-through (coalesced, all 256 threads, from staged LDS)
    const float S1 = sqrtf(1.f + EPSF);
#pragma unroll
    for (int e = 0; e < 4; ++e) {
        const int j = e*256 + t;
        const size_t ix1 = pb + (size_t)NN + n0 + j;
        const size_t ix2 = pb + (size_t)2*NN + n0 + j;
        out[ix1]          = S1 * uvS[j][0];
        out[OFF_MU + ix1] = 0.f;
        out[OFF_LV + ix1] = 0.f;
        out[ix2]          = S1 * uvS[j][1];
        out[OFF_MU + ix2] = 0.f;
        out[OFF_LV + ix2] = 0.f;
    }
}

extern "C" void kernel_launch(void* const* d_in, const int* in_sizes, int n_in,
                              void* d_out, int out_size, void* d_ws, size_t ws_size,
                              hipStream_t stream) {
    (void)in_sizes; (void)n_in; (void)out_size; (void)ws_size;
    const float* p = (const float*)d_in[0];
    const float* g = (const float*)d_in[1];
#define IN(i) ((const float*)d_in[i])
    float* ws  = (float*)d_ws;
    float* out = (float*)d_out;

    hipMemsetAsync(d_ws, 0, WS_ZERO_FLOATS * sizeof(float), stream);

    // combos: 0=lv_cw 1=lv_cb 2=mu_cw 3=mu_cb
    hipLaunchKernelGGL(k_filmA, dim3(4, 8), dim3(256), 0, stream,
                       g, IN(6), IN(11), IN(22), IN(27), ws);
    hipLaunchKernelGGL(k_filmB, dim3(4),    dim3(256), 0, stream,
                       IN(7),  IN(8),  IN(9),  IN(10),
                       IN(12), IN(13), IN(14), IN(15),
                       IN(23), IN(24), IN(25), IN(26),
                       IN(28), IN(29), IN(30), IN(31),
                       ws);
    hipLaunchKernelGGL(k_moments, dim3(512),  dim3(256), 0, stream, p, ws);
    hipLaunchKernelGGL(k_coef2,   dim3(4),    dim3(256), 0, stream,
                       IN(2), IN(3), IN(4), IN(18), IN(19), IN(20), IN(5), IN(21), ws);
    hipLaunchKernelGGL(k_h2stats, dim3(1024), dim3(256), 0, stream, p, ws);
    hipLaunchKernelGGL(k_redpc,   dim3(128),  dim3(256), 0, stream, IN(16), IN(32), ws);
    hipLaunchKernelGGL(k_main,    dim3(1024), dim3(256), 0, stream,
                       p, IN(17), IN(33), ws, out);
#undef IN
}

// Round 18
// 138.145 us; speedup vs baseline: 1.0600x; 1.0600x over previous
//
#include <hip/hip_runtime.h>
#include <math.h>

#define BB 64
#define FF 64
#define GG 512
#define NN 16384
#define PTOT (BB*NN)          // 1048576
#define EPSF 1e-6f
#define BN_EPSF 1e-5f

// ws float offsets
#define WS_HBUF   0           // [4][4096] film phase-1 partials (zeroed)
#define WS_MOM    16384       // 5 moments + pad -> 16392
#define WS_COEF   16648       // [2][64][4] (A,B,C,pad) -> 17160
#define WS_FILMW  17416       // [2][64*64] -> 25608
#define WS_FILMB  25608       // [2][64*64] -> 33800
#define WS_WB     33800       // bf16 W, ushort[2][64][64] = 4096 floats -> 37896
#define WS_PC     37896       // [2][64][64][4] {s,t,w2,0} -> 70664
#define WS_PART   70664       // [1024][4][64] h2stats partials -> 332808
#define WS_ZERO_FLOATS 16648

#define OFF_MU  (BB*3*NN)
#define OFF_LV  (2*BB*3*NN)

typedef __attribute__((ext_vector_type(8))) short short8_t;
typedef __attribute__((ext_vector_type(4))) float f32x4;

__device__ __forceinline__ unsigned int bf16u(float x) {
    unsigned int u = __float_as_uint(x);
    return ((u + 0x7FFFu + ((u >> 16) & 1u)) >> 16) & 0xFFFFu;   // RNE
}

// ---------------- FiLM phase 1: H_partial = g[:,kc] @ W0[:,kc]^T, K-split ----------------
__global__ __launch_bounds__(256) void k_filmA(
    const float* __restrict__ g,
    const float* __restrict__ W0_0, const float* __restrict__ W0_1,
    const float* __restrict__ W0_2, const float* __restrict__ W0_3,
    float* __restrict__ ws) {
    __shared__ float g_tile[64][65];
    __shared__ float wT[64][69];
    const int combo = blockIdx.x;
    const int kbase = blockIdx.y * 64;
    const int t = threadIdx.x;
    const float* W0 = combo==0 ? W0_0 : combo==1 ? W0_1 : combo==2 ? W0_2 : W0_3;
    float* hb = ws + WS_HBUF + combo*4096;

#pragma unroll
    for (int n = 0; n < 4; ++n) {
        const int idx = t + n*256;             // 0..1023 float4s
        const int row = idx >> 4, k4 = idx & 15;
        const float4 gv = *(const float4*)(g  + row*GG + kbase + k4*4);
        const float4 wv = *(const float4*)(W0 + row*GG + kbase + k4*4);
        g_tile[row][k4*4+0] = gv.x; g_tile[row][k4*4+1] = gv.y;
        g_tile[row][k4*4+2] = gv.z; g_tile[row][k4*4+3] = gv.w;
        wT[k4*4+0][row] = wv.x; wT[k4*4+1][row] = wv.y;
        wT[k4*4+2][row] = wv.z; wT[k4*4+3][row] = wv.w;
    }
    __syncthreads();

    const int b0 = (t >> 3) * 2, f0 = (t & 7) * 8;
    float acc[2][8];
#pragma unroll
    for (int i = 0; i < 2; ++i)
#pragma unroll
        for (int j = 0; j < 8; ++j) acc[i][j] = 0.f;
#pragma unroll 4
    for (int k = 0; k < 64; ++k) {
        const float g0 = g_tile[b0][k], g1 = g_tile[b0+1][k];
        const float4 w01 = *(const float4*)&wT[k][f0];
        const float4 w23 = *(const float4*)&wT[k][f0+4];
        const float wv[8] = {w01.x,w01.y,w01.z,w01.w,w23.x,w23.y,w23.z,w23.w};
#pragma unroll
        for (int j = 0; j < 8; ++j) {
            acc[0][j] = fmaf(g0, wv[j], acc[0][j]);
            acc[1][j] = fmaf(g1, wv[j], acc[1][j]);
        }
    }
#pragma unroll
    for (int i = 0; i < 2; ++i)
#pragma unroll
        for (int j = 0; j < 8; ++j)
            atomicAdd(&hb[(b0+i)*64 + f0+j], acc[i][j]);
}

// ---------------- FiLM phase 2+3: BN + SiLU + h @ W1^T + b1 ----------------
__global__ __launch_bounds__(256) void k_filmB(
    const float* __restrict__ bng_0, const float* __restrict__ bnb_0,
    const float* __restrict__ W1_0,  const float* __restrict__ b1_0,
    const float* __restrict__ bng_1, const float* __restrict__ bnb_1,
    const float* __restrict__ W1_1,  const float* __restrict__ b1_1,
    const float* __restrict__ bng_2, const float* __restrict__ bnb_2,
    const float* __restrict__ W1_2,  const float* __restrict__ b1_2,
    const float* __restrict__ bng_3, const float* __restrict__ bnb_3,
    const float* __restrict__ W1_3,  const float* __restrict__ b1_3,
    float* __restrict__ ws) {
    __shared__ float H[64][65];
    __shared__ float S[64][65];
    __shared__ float W1T[64][69];
    const int combo = blockIdx.x;
    const int t = threadIdx.x;
    const float* bng = combo==0 ? bng_0 : combo==1 ? bng_1 : combo==2 ? bng_2 : bng_3;
    const float* bnb = combo==0 ? bnb_0 : combo==1 ? bnb_1 : combo==2 ? bnb_2 : bnb_3;
    const float* W1  = combo==0 ? W1_0  : combo==1 ? W1_1  : combo==2 ? W1_2  : W1_3;
    const float* b1  = combo==0 ? b1_0  : combo==1 ? b1_1  : combo==2 ? b1_2  : b1_3;
    const float* hb  = ws + WS_HBUF + combo*4096;
    float* outp = ws + ((combo & 1) ? WS_FILMB : WS_FILMW) + (combo >> 1) * 4096;

    for (int idx = t; idx < 4096; idx += 256) H[idx >> 6][idx & 63] = hb[idx];
    {   // stage W1 transposed (W1 is 64x64: row = idx>>4, col4 = idx&15)
#pragma unroll
        for (int n = 0; n < 4; ++n) {
            const int idx = t + n*256;          // 0..1023 float4s
            const int f2 = idx >> 4, k4 = idx & 15;
            const float4 wv = *(const float4*)(W1 + f2*64 + k4*4);
            W1T[k4*4+0][f2] = wv.x; W1T[k4*4+1][f2] = wv.y;
            W1T[k4*4+2][f2] = wv.z; W1T[k4*4+3][f2] = wv.w;
        }
    }
    __syncthreads();
    for (int idx = t; idx < 4096; idx += 256) {
        const int b = idx >> 6, f = idx & 63;
        float m = 0.f;
        for (int b2 = 0; b2 < 64; ++b2) m += H[b2][f];
        m *= (1.f/64.f);
        float v = 0.f;
        for (int b2 = 0; b2 < 64; ++b2) { const float d = H[b2][f] - m; v = fmaf(d, d, v); }
        v *= (1.f/64.f);
        const float xh = (H[b][f] - m) * rsqrtf(v + BN_EPSF) * bng[f] + bnb[f];
        S[b][f] = xh / (1.f + expf(-xh));   // SiLU
    }
    __syncthreads();
    const int b0 = (t >> 3) * 2, f0 = (t & 7) * 8;
    float acc[2][8];
#pragma unroll
    for (int i = 0; i < 2; ++i)
#pragma unroll
        for (int j = 0; j < 8; ++j) acc[i][j] = 0.f;
#pragma unroll 4
    for (int k = 0; k < 64; ++k) {
        const float s0 = S[b0][k], s1 = S[b0+1][k];
        const float4 w01 = *(const float4*)&W1T[k][f0];
        const float4 w23 = *(const float4*)&W1T[k][f0+4];
        const float wv[8] = {w01.x,w01.y,w01.z,w01.w,w23.x,w23.y,w23.z,w23.w};
#pragma unroll
        for (int j = 0; j < 8; ++j) {
            acc[0][j] = fmaf(s0, wv[j], acc[0][j]);
            acc[1][j] = fmaf(s1, wv[j], acc[1][j]);
        }
    }
#pragma unroll
    for (int i = 0; i < 2; ++i)
#pragma unroll
        for (int j = 0; j < 8; ++j)
            outp[(b0+i)*64 + f0+j] = acc[i][j] + b1[f0+j];
}

// ---------------- global moments of (u,v) ----------------
__global__ __launch_bounds__(256) void k_moments(const float* __restrict__ p, float* __restrict__ ws) {
    __shared__ float red[4][8];
    const int t = threadIdx.x;
    const int gid = blockIdx.x * 256 + t;      // 131072 threads, 8 pos each
    const int pos8 = gid << 3;
    const int b = pos8 >> 14, n = pos8 & 16383;
    const float* base = p + (size_t)b*3*NN + NN + n;
    const float4 ua = *(const float4*)base;
    const float4 ub = *(const float4*)(base + 4);
    const float4 va = *(const float4*)(base + NN);
    const float4 vb = *(const float4*)(base + NN + 4);
    float su  = (ua.x+ua.y)+(ua.z+ua.w)+(ub.x+ub.y)+(ub.z+ub.w);
    float sv  = (va.x+va.y)+(va.z+va.w)+(vb.x+vb.y)+(vb.z+vb.w);
    float suu = fmaf(ua.x,ua.x, fmaf(ua.y,ua.y, fmaf(ua.z,ua.z, ua.w*ua.w)))
              + fmaf(ub.x,ub.x, fmaf(ub.y,ub.y, fmaf(ub.z,ub.z, ub.w*ub.w)));
    float svv = fmaf(va.x,va.x, fmaf(va.y,va.y, fmaf(va.z,va.z, va.w*va.w)))
              + fmaf(vb.x,vb.x, fmaf(vb.y,vb.y, fmaf(vb.z,vb.z, vb.w*vb.w)));
    float suv = fmaf(ua.x,va.x, fmaf(ua.y,va.y, fmaf(ua.z,va.z, ua.w*va.w)))
              + fmaf(ub.x,vb.x, fmaf(ub.y,vb.y, fmaf(ub.z,vb.z, ub.w*vb.w)));
#pragma unroll
    for (int off = 32; off > 0; off >>= 1) {
        su  += __shfl_down(su,  off);
        sv  += __shfl_down(sv,  off);
        suu += __shfl_down(suu, off);
        svv += __shfl_down(svv, off);
        suv += __shfl_down(suv, off);
    }
    const int w = t >> 6;
    if ((t & 63) == 0) {
        red[w][0] = su; red[w][1] = sv; red[w][2] = suu; red[w][3] = svv; red[w][4] = suv;
    }
    __syncthreads();
    if (t < 5)
        atomicAdd(&ws[WS_MOM + t], red[0][t] + red[1][t] + red[2][t] + red[3][t]);
}

// ---------------- BN1 coefs (closed form from moments); build bf16 W ----------------
__global__ __launch_bounds__(256) void k_coef2(const float* __restrict__ lvW, const float* __restrict__ lvG,
                                               const float* __restrict__ lvB, const float* __restrict__ muW,
                                               const float* __restrict__ muG, const float* __restrict__ muB,
                                               const float* __restrict__ lvW1, const float* __restrict__ muW1,
                                               float* __restrict__ ws) {
    const int t = threadIdx.x;
    const int bid = blockIdx.x;
    if (bid == 0 && t < 128) {
        const int br = t >> 6, c = t & 63;
        const float* W  = br ? muW : lvW;
        const float* Gp = br ? muG : lvG;
        const float* Bp = br ? muB : lvB;
        const float inv = 1.f / (float)PTOT;
        const float Eu  = ws[WS_MOM+0]*inv, Ev  = ws[WS_MOM+1]*inv;
        const float Euu = ws[WS_MOM+2]*inv, Evv = ws[WS_MOM+3]*inv, Euv = ws[WS_MOM+4]*inv;
        const float w0 = W[c*2 + 0], w1 = W[c*2 + 1];
        const float m   = w0*Eu + w1*Ev;
        const float e2  = w0*w0*Euu + 2.f*w0*w1*Euv + w1*w1*Evv;
        const float var = e2 - m*m;
        const float rs  = rsqrtf(var + BN_EPSF);
        const float ga = Gp[c], be = Bp[c];
        float4 cf;
        cf.x = w0*rs*ga; cf.y = w1*rs*ga; cf.z = be - m*rs*ga; cf.w = 0.f;
        *(float4*)(ws + WS_COEF + (br*64+c)*4) = cf;
    }
    // bf16 copy of sd1_W, row-major [br][c][k] — disjoint 2048-element slices per block
    unsigned short* wb = (unsigned short*)(ws + WS_WB);
    for (int e = bid*2048 + t; e < bid*2048 + 2048; e += 256) {
        const int brx = e >> 12, r = e & 4095;
        wb[e] = (unsigned short)bf16u((brx ? muW1 : lvW1)[r]);
    }
}

// ---------------- BN2 stats: dual-branch LDS-staged MFMA; NO atomics (disjoint partials) ----------------
__global__ __launch_bounds__(256) void k_h2stats(const float* __restrict__ p, float* __restrict__ ws) {
    __shared__ float uS[1024], vS[1024];
    __shared__ float red1[2][4][64];
    __shared__ float red2[2][4][64];
    const int t = threadIdx.x;
    const int bid = blockIdx.x;
    const int b = bid >> 4;
    const int n0 = (bid & 15) * 1024;          // 1024 positions per block
    const float* pk = p + (size_t)b*3*NN + NN;
    // stage u,v coalesced
    *(float4*)&uS[t*4] = *(const float4*)(pk + n0 + t*4);
    *(float4*)&vS[t*4] = *(const float4*)(pk + NN + n0 + t*4);
    __syncthreads();
    const int w = t >> 6, lane = t & 63, g = lane >> 4, col = lane & 15;
    const unsigned short* wbg = (const unsigned short*)(ws + WS_WB);

#pragma unroll 1
    for (int br = 0; br < 2; ++br) {
        float cA[16], cB[16], cC[16];
#pragma unroll
        for (int kt = 0; kt < 2; ++kt)
#pragma unroll
            for (int j = 0; j < 8; ++j) {
                const int i = kt*8 + j, ch = kt*32 + g*8 + j;
                const float4 cf = *(const float4*)(ws + WS_COEF + (br*64 + ch)*4);
                cA[i] = cf.x; cB[i] = cf.y; cC[i] = cf.z;
            }
        short8_t a[4][2];
#pragma unroll
        for (int mt = 0; mt < 4; ++mt)
#pragma unroll
            for (int kt = 0; kt < 2; ++kt)
                a[mt][kt] = *(const short8_t*)(wbg + br*4096 + (mt*16+col)*64 + kt*32 + g*8);
        float s1v[16], s2v[16];
#pragma unroll
        for (int i = 0; i < 16; ++i) { s1v[i] = 0.f; s2v[i] = 0.f; }

#pragma unroll 4
        for (int nt = 0; nt < 16; ++nt) {      // wave-owned n-tiles
            const int pl = (nt*4 + w)*16 + col;
            const float u = uS[pl], v = vS[pl];
            union { uint4 u4; short8_t s8; } bf[2];
#pragma unroll
            for (int kt = 0; kt < 2; ++kt) {
                unsigned int dw[4];
#pragma unroll
                for (int q = 0; q < 4; ++q) {
                    const int i0 = kt*8 + q*2;
                    const float h0 = fmaxf(fmaf(cA[i0],   u, fmaf(cB[i0],   v, cC[i0])),   0.f);
                    const float h1 = fmaxf(fmaf(cA[i0+1], u, fmaf(cB[i0+1], v, cC[i0+1])), 0.f);
                    asm("v_cvt_pk_bf16_f32 %0, %1, %2" : "=v"(dw[q]) : "v"(h0), "v"(h1));
                }
                bf[kt].u4 = make_uint4(dw[0], dw[1], dw[2], dw[3]);
            }
            f32x4 acc[4];
#pragma unroll
            for (int mt = 0; mt < 4; ++mt) { f32x4 z = {0.f,0.f,0.f,0.f}; acc[mt] = z; }
#pragma unroll
            for (int mt = 0; mt < 4; ++mt) {
                acc[mt] = __builtin_amdgcn_mfma_f32_16x16x32_bf16(a[mt][0], bf[0].s8, acc[mt], 0,0,0);
                acc[mt] = __builtin_amdgcn_mfma_f32_16x16x32_bf16(a[mt][1], bf[1].s8, acc[mt], 0,0,0);
            }
#pragma unroll
            for (int mt = 0; mt < 4; ++mt)
#pragma unroll
                for (int r = 0; r < 4; ++r) {
                    const int i = mt*4 + r;
                    const float x = acc[mt][r];
                    s1v[i] += x;
                    s2v[i] = fmaf(x, x, s2v[i]);
                }
        }
#pragma unroll
        for (int i = 0; i < 16; ++i) {
#pragma unroll
            for (int off = 1; off <= 8; off <<= 1) {
                s1v[i] += __shfl_xor(s1v[i], off);
                s2v[i] += __shfl_xor(s2v[i], off);
            }
        }
        if (col == 0) {
#pragma unroll
            for (int mt = 0; mt < 4; ++mt)
#pragma unroll
                for (int r = 0; r < 4; ++r) {
                    const int c = mt*16 + g*4 + r;
                    red1[br][w][c] = s1v[mt*4+r];
                    red2[br][w][c] = s2v[mt*4+r];
                }
        }
    }
    __syncthreads();
    {   // disjoint per-block partial store: [bid][kind][c], kind = br*2 + (0:s1,1:s2)
        const int kind = t >> 6, c = t & 63;
        const int br2 = kind >> 1, sk = kind & 1;
        const float* rr = sk ? &red2[br2][0][0] : &red1[br2][0][0];
        ws[WS_PART + bid*256 + (br2*2 + sk)*64 + c] =
            rr[0*64 + c] + rr[1*64 + c] + rr[2*64 + c] + rr[3*64 + c];
    }
}

// ---------------- reduce partials -> stats -> PC table (one block per (br,c)) ----------------
__global__ __launch_bounds__(256) void k_redpc(const float* __restrict__ lv_sd2W,
                                               const float* __restrict__ mu_sd2W,
                                               float* __restrict__ ws) {
    __shared__ float a1[4], a2[4];
    __shared__ float stats[2];
    const int idx = blockIdx.x;        // 0..127 => br*64 + c
    const int br = idx >> 6, c = idx & 63;
    const int t = threadIdx.x;
    float s1 = 0.f, s2 = 0.f;
    for (int j = t; j < 1024; j += 256) {
        const float* pp = ws + WS_PART + j*256;
        s1 += pp[(br*2 + 0)*64 + c];
        s2 += pp[(br*2 + 1)*64 + c];
    }
#pragma unroll
    for (int off = 32; off > 0; off >>= 1) {
        s1 += __shfl_down(s1, off);
        s2 += __shfl_down(s2, off);
    }
    if ((t & 63) == 0) { a1[t >> 6] = s1; a2[t >> 6] = s2; }
    __syncthreads();
    if (t == 0) {
        const float S1 = a1[0]+a1[1]+a1[2]+a1[3];
        const float S2 = a2[0]+a2[1]+a2[2]+a2[3];
        const float inv = 1.f / (float)PTOT;
        const float m2 = S1 * inv, e2 = S2 * inv;
        stats[0] = m2;
        stats[1] = rsqrtf(e2 - m2*m2 + BN_EPSF);
    }
    __syncthreads();
    if (t < 64) {   // PC[br][b][c] for all 64 batches of this (br,c)
        const int b = t;
        const float m2  = stats[0], rs2 = stats[1];
        const float fw  = ws[WS_FILMW + br*4096 + b*64 + c];
        const float fb  = ws[WS_FILMB + br*4096 + b*64 + c];
        const float s = (EPSF + expf(fw)) * rs2;
        float4 pc;
        pc.x = s; pc.y = fb - s*m2; pc.z = (br ? mu_sd2W : lv_sd2W)[c]; pc.w = 0.f;
        *(float4*)(ws + WS_PC + ((br*64 + b)*64 + c)*4) = pc;
    }
}

// ---------------- main pass: LDS-staged wave-parallel MFMA + fused epilogue ----------------
__global__ __launch_bounds__(256) void k_main(
    const float* __restrict__ p,
    const float* __restrict__ lv_sd2b, const float* __restrict__ mu_sd2b,
    const float* __restrict__ ws, float* __restrict__ out)
{
    __shared__ float xS[1024], uS[1024], vS[1024];
    __shared__ __align__(16) float pcS[2][64][4];
    __shared__ float resS[1024];

    const int t   = threadIdx.x;
    const int bid = blockIdx.x;
    const int b   = bid >> 4;
    const int n0  = (bid & 15) * 1024;         // 1024 positions per block
    const size_t pb = (size_t)b * 3 * NN;
    const float* pk = p + pb + NN;

    // stage x0,u,v coalesced + per-(br,c) epilogue constants
    *(float4*)&xS[t*4] = *(const float4*)(p + pb + n0 + t*4);
    *(float4*)&uS[t*4] = *(const float4*)(pk + n0 + t*4);
    *(float4*)&vS[t*4] = *(const float4*)(pk + NN + n0 + t*4);
    if (t < 128) {
        const int br = t >> 6, c = t & 63;
        *(float4*)&pcS[br][c][0] = *(const float4*)(ws + WS_PC + ((br*64 + b)*64 + c)*4);
    }
    __syncthreads();

    const int w = t >> 6, lane = t & 63, g = lane >> 4, col = lane & 15;
    const unsigned short* wbg = (const unsigned short*)(ws + WS_WB);
    const float sd2b0 = lv_sd2b[0], sd2b1 = mu_sd2b[0];

#pragma unroll 1
    for (int br = 0; br < 2; ++br) {
        float cA[16], cB[16], cC[16];
#pragma unroll
        for (int kt = 0; kt < 2; ++kt)
#pragma unroll
            for (int j = 0; j < 8; ++j) {
                const int i = kt*8 + j, ch = kt*32 + g*8 + j;
                const float4 cf = *(const float4*)(ws + WS_COEF + (br*64 + ch)*4);
                cA[i] = cf.x; cB[i] = cf.y; cC[i] = cf.z;
            }
        short8_t a[4][2];
#pragma unroll
        for (int mt = 0; mt < 4; ++mt)
#pragma unroll
            for (int kt = 0; kt < 2; ++kt)
                a[mt][kt] = *(const short8_t*)(wbg + br*4096 + (mt*16+col)*64 + kt*32 + g*8);
        float sp[16], tq[16], w2v[16];
#pragma unroll
        for (int mt = 0; mt < 4; ++mt)
#pragma unroll
            for (int r = 0; r < 4; ++r) {
                const int i = mt*4 + r, c = mt*16 + g*4 + r;
                const float4 pc = *(const float4*)&pcS[br][c][0];
                sp[i] = pc.x; tq[i] = pc.y; w2v[i] = pc.z;
            }

#pragma unroll 4
        for (int nt = 0; nt < 16; ++nt) {      // wave-owned n-tiles
            const int pl = (nt*4 + w)*16 + col;
            const float u = uS[pl], v = vS[pl];
            union { uint4 u4; short8_t s8; } bf[2];
#pragma unroll
            for (int kt = 0; kt < 2; ++kt) {
                unsigned int dw[4];
#pragma unroll
                for (int q = 0; q < 4; ++q) {
                    const int i0 = kt*8 + q*2;
                    const float h0 = fmaxf(fmaf(cA[i0],   u, fmaf(cB[i0],   v, cC[i0])),   0.f);
                    const float h1 = fmaxf(fmaf(cA[i0+1], u, fmaf(cB[i0+1], v, cC[i0+1])), 0.f);
                    asm("v_cvt_pk_bf16_f32 %0, %1, %2" : "=v"(dw[q]) : "v"(h0), "v"(h1));
                }
                bf[kt].u4 = make_uint4(dw[0], dw[1], dw[2], dw[3]);
            }
            f32x4 acc[4];
#pragma unroll
            for (int mt = 0; mt < 4; ++mt) { f32x4 z = {0.f,0.f,0.f,0.f}; acc[mt] = z; }
#pragma unroll
            for (int mt = 0; mt < 4; ++mt) {
                acc[mt] = __builtin_amdgcn_mfma_f32_16x16x32_bf16(a[mt][0], bf[0].s8, acc[mt], 0,0,0);
                acc[mt] = __builtin_amdgcn_mfma_f32_16x16x32_bf16(a[mt][1], bf[1].s8, acc[mt], 0,0,0);
            }
            float po0 = 0.f, po1 = 0.f;
#pragma unroll
            for (int mt = 0; mt < 4; ++mt)
#pragma unroll
                for (int r = 0; r < 4; r += 2) {
                    const int i = mt*4 + r;
                    const float hf0 = fmaf(acc[mt][r],   sp[i],   tq[i]);
                    const float hf1 = fmaf(acc[mt][r+1], sp[i+1], tq[i+1]);
                    po0 = fmaf(fmaxf(hf0, 0.f), w2v[i],   po0);
                    po1 = fmaf(fmaxf(hf1, 0.f), w2v[i+1], po1);
                }
            float po = po0 + po1;
            po += __shfl_xor(po, 16);
            po += __shfl_xor(po, 32);
            if (br == 0) {
                if (lane < 16) resS[pl] = po;    // same-wave write/read, no barrier needed
            } else {
                const float ol = resS[pl] + sd2b0;
                const float om = po + sd2b1;
                const float lw = ol / (1.f + fabsf(ol));
                const float sc = sqrtf(EPSF + expf(lw));
                const size_t nix = pb + n0 + pl;
                if (g == 0) {
                    out[nix] = fmaf(sc, xS[pl], om);
                } else if (g == 1) {
                    out[OFF_MU + nix] = om;
                } else if (g == 2) {
                    out[OFF_LV + nix] = lw;
                }
            }
        }
    }
    // channels 1,2 pass-through (coalesced, all 256 threads, from staged LDS)
    const float S1 = sqrtf(1.f + EPSF);
#pragma unroll
    for (int e = 0; e < 4; ++e) {
        const int j = e*256 + t;
        const size_t ix1 = pb + (size_t)NN + n0 + j;
        const size_t ix2 = pb + (size_t)2*NN + n0 + j;
        out[ix1]          = S1 * uS[j];
        out[OFF_MU + ix1] = 0.f;
        out[OFF_LV + ix1] = 0.f;
        out[ix2]          = S1 * vS[j];
        out[OFF_MU + ix2] = 0.f;
        out[OFF_LV + ix2] = 0.f;
    }
}

extern "C" void kernel_launch(void* const* d_in, const int* in_sizes, int n_in,
                              void* d_out, int out_size, void* d_ws, size_t ws_size,
                              hipStream_t stream) {
    (void)in_sizes; (void)n_in; (void)out_size; (void)ws_size;
    const float* p = (const float*)d_in[0];
    const float* g = (const float*)d_in[1];
#define IN(i) ((const float*)d_in[i])
    float* ws  = (float*)d_ws;
    float* out = (float*)d_out;

    hipMemsetAsync(d_ws, 0, WS_ZERO_FLOATS * sizeof(float), stream);

    // combos: 0=lv_cw 1=lv_cb 2=mu_cw 3=mu_cb
    hipLaunchKernelGGL(k_filmA, dim3(4, 8), dim3(256), 0, stream,
                       g, IN(6), IN(11), IN(22), IN(27), ws);
    hipLaunchKernelGGL(k_filmB, dim3(4),    dim3(256), 0, stream,
                       IN(7),  IN(8),  IN(9),  IN(10),
                       IN(12), IN(13), IN(14), IN(15),
                       IN(23), IN(24), IN(25), IN(26),
                       IN(28), IN(29), IN(30), IN(31),
                       ws);
    hipLaunchKernelGGL(k_moments, dim3(512),  dim3(256), 0, stream, p, ws);
    hipLaunchKernelGGL(k_coef2,   dim3(4),    dim3(256), 0, stream,
                       IN(2), IN(3), IN(4), IN(18), IN(19), IN(20), IN(5), IN(21), ws);
    hipLaunchKernelGGL(k_h2stats, dim3(1024), dim3(256), 0, stream, p, ws);
    hipLaunchKernelGGL(k_redpc,   dim3(128),  dim3(256), 0, stream, IN(16), IN(32), ws);
    hipLaunchKernelGGL(k_main,    dim3(1024), dim3(256), 0, stream,
                       p, IN(17), IN(33), ws, out);
#undef IN
}